// Round 8
// baseline (631.926 us; speedup 1.0000x reference)
//
#include <hip/hip_runtime.h>
#include <hip/hip_bf16.h>

using short8 = __attribute__((ext_vector_type(8))) short;
using f32x4  = __attribute__((ext_vector_type(4))) float;

#define KLP 136   // padded K=128 row stride for LSTM

__device__ __forceinline__ unsigned short f2bf(float f) {
  unsigned u = __float_as_uint(f);
  u += 0x7FFFu + ((u >> 16) & 1u);
  return (unsigned short)(u >> 16);
}
__device__ __forceinline__ unsigned pack2(float a, float b) {
  return (unsigned)f2bf(a) | ((unsigned)f2bf(b) << 16);
}
#if __has_builtin(__builtin_amdgcn_rcpf)
__device__ __forceinline__ float fast_rcp(float x) { return __builtin_amdgcn_rcpf(x); }
#else
__device__ __forceinline__ float fast_rcp(float x) { return 1.f / x; }
#endif
__device__ __forceinline__ float sigm(float x) { return fast_rcp(1.f + __expf(-x)); }
__device__ __forceinline__ float tanh_f(float x) { return fmaf(2.f, sigm(2.f * x), -1.f); }

// ---------------- prep: simple transposes + bf16 casts ----------------
__global__ __launch_bounds__(256) void prep_simple(
    const float* __restrict__ W1_0, const float* __restrict__ Wih0,
    const float* __restrict__ bih0, const float* __restrict__ bhh0,
    const float* __restrict__ W1_1, const float* __restrict__ Wih1,
    const float* __restrict__ bih1, const float* __restrict__ bhh1,
    const float* __restrict__ gmW, const float* __restrict__ fmW,
    unsigned short* __restrict__ W1T,  // [2][64*160] out-major
    unsigned short* __restrict__ WcT,  // [2][256*128] out-major (x-part cols 0..63)
    float* __restrict__ bG,            // [2][256]
    unsigned short* __restrict__ WrT)  // [128][64]
{
  int t = blockIdx.x * 256 + threadIdx.x;
  const int per = 10240 + 16384 + 256;  // 26880
  if (t >= 2 * per + 8192) return;
  if (t >= 2 * per) {
    int r2 = t - 2 * per;
    int o = r2 >> 6, k = r2 & 63;
    float v = 0.f;
    if (o < 50) v = gmW[k * 50 + o];
    else if (o >= 64 && o < 114) v = fmW[k * 50 + (o - 64)];
    WrT[o * 64 + k] = f2bf(v);
    return;
  }
  int step = t / per, r = t % per;
  const float* W1  = step ? W1_1 : W1_0;
  const float* Wih = step ? Wih1 : Wih0;
  const float* bih = step ? bih1 : bih0;
  const float* bhh = step ? bhh1 : bhh0;
  if (r < 10240) {
    int o = r / 160, k = r % 160;
    W1T[step * 10240 + o * 160 + k] = f2bf(W1[k * 64 + o]);
  } else if (r < 26624) {
    int rr = r - 10240;
    int g = rr >> 6, k = rr & 63;
    WcT[step * 32768 + g * 128 + k] = f2bf(Wih[k * 256 + g]);
  } else {
    int g = r - 26624;
    bG[step * 256 + g] = bih[g] + bhh[g];
  }
}

// ---------------- prep: merged weight  Wc_h' = W2 @ Whh,  b2h = b2 @ Whh ----------------
__global__ __launch_bounds__(256) void prep_merge(
    const float* __restrict__ W2_0, const float* __restrict__ Whh0, const float* __restrict__ b2_0,
    const float* __restrict__ W2_1, const float* __restrict__ Whh1, const float* __restrict__ b2_1,
    unsigned short* __restrict__ WcT,  // [2][256*128] (h-part cols 64..127)
    float* __restrict__ b2h)           // [2][256]
{
  int t = blockIdx.x * 256 + threadIdx.x;
  if (t < 32768) {
    int step = t >> 14, r = t & 16383;
    int g = r >> 6, k = r & 63;
    const float* W2  = step ? W2_1 : W2_0;
    const float* Whh = step ? Whh1 : Whh0;
    float v = 0.f;
    for (int j = 0; j < 64; ++j) v = fmaf(W2[k * 64 + j], Whh[j * 256 + g], v);
    WcT[step * 32768 + g * 128 + 64 + k] = f2bf(v);
  } else if (t < 33280) {
    int r = t - 32768;
    int step = r >> 8, g = r & 255;
    const float* b2  = step ? b2_1 : b2_0;
    const float* Whh = step ? Whh1 : Whh0;
    float v = 0.f;
    for (int j = 0; j < 64; ++j) v = fmaf(b2[j], Whh[j * 256 + g], v);
    b2h[step * 256 + g] = v;
  }
}

__global__ __launch_bounds__(256) void convert_x(
    const float* __restrict__ x, unsigned short* __restrict__ xb, int n)
{
  int i = blockIdx.x * 256 + threadIdx.x;
  if (i < n) xb[i] = f2bf(x[i]);
}

// ---------------- sort: hist -> 3-phase scan (+segment build) -> eid+src scatter ----------------
__global__ __launch_bounds__(256) void hist_kernel(
    const int* __restrict__ dstI, int* __restrict__ hist, int E)
{
  int e = blockIdx.x * 256 + threadIdx.x;
  if (e < E) atomicAdd(&hist[dstI[e]], 1);
}

__global__ __launch_bounds__(256) void scan_part(
    const int* __restrict__ hist, int2* __restrict__ blockTot, int N)
{
  __shared__ int sD[256], sS[256];
  int t = threadIdx.x;
  int n = blockIdx.x * 256 + t;
  int d = (n < N) ? hist[n] : 0;
  int sg = (d + 15) >> 4;
  sD[t] = d; sS[t] = sg;
  __syncthreads();
  #pragma unroll
  for (int off = 128; off; off >>= 1) {
    if (t < off) { sD[t] += sD[t + off]; sS[t] += sS[t + off]; }
    __syncthreads();
  }
  if (t == 0) blockTot[blockIdx.x] = make_int2(sD[0], sS[0]);
}

__global__ __launch_bounds__(256) void scan_mid(
    const int2* __restrict__ blockTot, int2* __restrict__ blockBase,
    int* __restrict__ nSegTot, int nb)
{
  __shared__ int sD[256], sS[256];
  int t = threadIdx.x;
  int d = 0, s = 0;
  if (t < nb) { int2 v = blockTot[t]; d = v.x; s = v.y; }
  sD[t] = d; sS[t] = s;
  __syncthreads();
  #pragma unroll
  for (int off = 1; off < 256; off <<= 1) {
    int vd = (t >= off) ? sD[t - off] : 0;
    int vs = (t >= off) ? sS[t - off] : 0;
    __syncthreads();
    sD[t] += vd; sS[t] += vs;
    __syncthreads();
  }
  if (t < nb) blockBase[t] = make_int2(sD[t] - d, sS[t] - s);
  if (t == nb - 1) *nSegTot = sS[t];
}

__global__ __launch_bounds__(256) void scan_final(
    const int* __restrict__ hist, const int2* __restrict__ blockBase,
    int* __restrict__ cursor, int4* __restrict__ segInfo, int N)
{
  __shared__ int sD[256], sS[256];
  int t = threadIdx.x;
  int n = blockIdx.x * 256 + t;
  int d = (n < N) ? hist[n] : 0;
  int sg = (d + 15) >> 4;
  sD[t] = d; sS[t] = sg;
  __syncthreads();
  #pragma unroll
  for (int off = 1; off < 256; off <<= 1) {
    int vd = (t >= off) ? sD[t - off] : 0;
    int vs = (t >= off) ? sS[t - off] : 0;
    __syncthreads();
    sD[t] += vd; sS[t] += vs;
    __syncthreads();
  }
  if (n < N) {
    int2 bb = blockBase[blockIdx.x];
    int degBase = bb.x + sD[t] - d;
    int segBase = bb.y + sS[t] - sg;
    cursor[n] = degBase;
    for (int j = 0; j < sg; ++j)
      segInfo[segBase + j] = make_int4(degBase + j * 16, n, min(d - j * 16, 16), 0);
  }
}

// scatter the 4B edge id AND 4B src (the single random-write pass)
__global__ __launch_bounds__(256) void scatter_eid2(
    const int* __restrict__ srcI, const int* __restrict__ dstI,
    int* __restrict__ cursor,
    int* __restrict__ eidS, int* __restrict__ srcS, int E)
{
  int e = blockIdx.x * 256 + threadIdx.x;
  if (e >= E) return;
  int d = dstI[e];
  int sv = srcI[e];
  int p = atomicAdd(&cursor[d], 1);
  eidS[p] = e;
  srcS[p] = sv;
}

// ---------------- edge GEMM v3: 2 segments/wave, W1 in LDS, direct ea reads ----------------
__global__ __launch_bounds__(256, 4) void edge_gemm2(
    const unsigned short* __restrict__ xb,     // [N][64] bf16
    const float* __restrict__ ea,              // [E][32] f32, ORIGINAL order
    const int* __restrict__ eidS,              // [E] edge ids sorted by dst
    const int* __restrict__ srcS,              // [E] src sorted by dst
    const int4* __restrict__ segInfo,          // [nSeg] {start,node,cnt,_}
    const int* __restrict__ nSegPtr,
    const unsigned short* __restrict__ W1T,    // [64][160] bf16 out-major
    const float* __restrict__ b1,
    float* __restrict__ aggrH)                 // [N][64] f32 (pre-zeroed)
{
  __shared__ unsigned short sW1[64 * 21 * 8];  // 21 uint4 per 160-elem row (padded)
  const int t = threadIdx.x;
  {
    const uint4* gw1 = (const uint4*)W1T;      // 1280 uint4, 20/row
    uint4* lw1 = (uint4*)sW1;
    #pragma unroll
    for (int pp = 0; pp < 5; ++pp) {
      int idx = t + pp * 256;
      int o = idx / 20, s = idx % 20;
      lw1[o * 21 + s] = gw1[idx];
    }
  }
  const int w = t >> 6, l = t & 63;
  const int quad = l >> 4, lr = l & 15;
  float bb[4];
  #pragma unroll
  for (int n = 0; n < 4; ++n) bb[n] = b1[n * 16 + lr];
  __syncthreads();

  const int nSeg = *nSegPtr;
  const int nPair = (nSeg + 1) >> 1;
  const int P = gridDim.x * 4;
  int p = blockIdx.x * 4 + w;
  if (p >= nPair) return;

  int4 si0 = segInfo[p * 2];
  int4 si1 = (p * 2 + 1 < nSeg) ? segInfo[p * 2 + 1] : make_int4(si0.x, si0.y, 0, 0);

  while (true) {
    const int pn = p + P;
    const bool more = pn < nPair;
    int4 n_si0, n_si1;
    if (more) {
      n_si0 = segInfo[pn * 2];
      n_si1 = (pn * 2 + 1 < nSeg) ? segInfo[pn * 2 + 1] : make_int4(n_si0.x, n_si0.y, 0, 0);
    }

    const int start0 = si0.x, node0 = si0.y, cnt0 = si0.z;
    const int start1 = si1.x, node1 = si1.y, cnt1 = si1.z;
    const int er0 = min(lr, cnt0 - 1);
    const int er1 = (cnt1 > 0) ? min(lr, cnt1 - 1) : 0;
    const int base1 = (cnt1 > 0) ? start1 : start0;

    // level-1 loads (coalesced over lr; 4-way quad broadcast)
    const int eid0 = eidS[start0 + er0];
    const int src0 = srcS[start0 + er0];
    const int eid1 = eidS[base1 + er1];
    const int src1 = srcS[base1 + er1];

    // level-2 gathers — all independent, issue together
    const short8* pd0 = (const short8*)(xb + (long long)node0 * 64);
    const short8* ps0 = (const short8*)(xb + (long long)src0 * 64);
    const float4* pe0 = (const float4*)(ea + (long long)eid0 * 32) + quad * 2;
    const short8* pd1 = (const short8*)(xb + (long long)node1 * 64);
    const short8* ps1 = (const short8*)(xb + (long long)src1 * 64);
    const float4* pe1 = (const float4*)(ea + (long long)eid1 * 32) + quad * 2;

    short8 A0[5], A1[5];
    A0[0] = pd0[quad];     A1[0] = pd1[quad];
    A0[1] = pd0[4 + quad]; A1[1] = pd1[4 + quad];
    A0[2] = ps0[quad];     A1[2] = ps1[quad];
    A0[3] = ps0[4 + quad]; A1[3] = ps1[4 + quad];
    float4 e00 = pe0[0], e01 = pe0[1];
    float4 e10 = pe1[0], e11 = pe1[1];
    union { uint4 u; short8 s8; } c0, c1;
    c0.u = make_uint4(pack2(e00.x, e00.y), pack2(e00.z, e00.w),
                      pack2(e01.x, e01.y), pack2(e01.z, e01.w));
    c1.u = make_uint4(pack2(e10.x, e10.y), pack2(e10.z, e10.w),
                      pack2(e11.x, e11.y), pack2(e11.z, e11.w));
    A0[4] = c0.s8; A1[4] = c1.s8;

    // 20 ds_read_b128 feed 40 MFMAs (B shared across both segments)
    f32x4 acc0[4] = {}, acc1[4] = {};
    #pragma unroll
    for (int kc = 0; kc < 5; ++kc) {
      #pragma unroll
      for (int n = 0; n < 4; ++n) {
        short8 bf = *(const short8*)(sW1 + ((n * 16 + lr) * 21 + kc * 4 + quad) * 8);
        acc0[n] = __builtin_amdgcn_mfma_f32_16x16x32_bf16(A0[kc], bf, acc0[n], 0, 0, 0);
        acc1[n] = __builtin_amdgcn_mfma_f32_16x16x32_bf16(A1[kc], bf, acc1[n], 0, 0, 0);
      }
    }

    // relu + mask pad rows + reduce 16 rows -> one atomic per column per segment
    #pragma unroll
    for (int n = 0; n < 4; ++n) {
      float s0v = 0.f, s1v = 0.f;
      #pragma unroll
      for (int rr = 0; rr < 4; ++rr) {
        int rowi = quad * 4 + rr;
        float v0 = fmaxf(acc0[n][rr] + bb[n], 0.f);
        float v1 = fmaxf(acc1[n][rr] + bb[n], 0.f);
        s0v += (rowi < cnt0) ? v0 : 0.f;
        s1v += (rowi < cnt1) ? v1 : 0.f;
      }
      s0v += __shfl_xor(s0v, 16);
      s0v += __shfl_xor(s0v, 32);
      s1v += __shfl_xor(s1v, 16);
      s1v += __shfl_xor(s1v, 32);
      if (quad == 0) {
        unsafeAtomicAdd(&aggrH[(long long)node0 * 64 + n * 16 + lr], s0v);
        if (cnt1 > 0)
          unsafeAtomicAdd(&aggrH[(long long)node1 * 64 + n * 16 + lr], s1v);
      }
    }

    if (!more) break;
    si0 = n_si0; si1 = n_si1; p = pn;
  }
}

// ---------------- LSTM cell: gates = [x | G] @ Wc' + bG + deg*b2h (bf16 h-path) ----------------
__global__ __launch_bounds__(256) void lstm3(
    const unsigned short* __restrict__ xbin,  // [N][64] bf16
    const float* __restrict__ aggrH,          // [N][64] f32 (Sum relu h1)
    const float* __restrict__ cin,            // may be null (c=0)
    float* __restrict__ cout,
    const unsigned short* __restrict__ WcT,   // [256][128] bf16 out-major (merged)
    const float* __restrict__ bG,             // [256]
    const float* __restrict__ b2h,            // [256]
    const int* __restrict__ degA,             // [N]
    unsigned short* __restrict__ xbout,       // [N][64] bf16
    int nNodes)
{
  __shared__ unsigned short sIn[64 * KLP];
  __shared__ unsigned short sW[64 * KLP];
  __shared__ float sBG[256], sB2h[256];
  const int t = threadIdx.x;
  sBG[t] = bG[t];
  sB2h[t] = b2h[t];

  const int base_n = blockIdx.x * 64;
  const int nl = t >> 2, q = t & 3;
  const int node = base_n + nl;
  unsigned short* rowp = sIn + nl * KLP;
  if (node < nNodes) {
    const uint4* px = (const uint4*)(xbin + (long long)node * 64);
    *(uint4*)(rowp + q * 16)     = px[q * 2];
    *(uint4*)(rowp + q * 16 + 8) = px[q * 2 + 1];
    const float4* pg = (const float4*)(aggrH + (long long)node * 64) + q * 4;
    float4 g0 = pg[0], g1 = pg[1], g2 = pg[2], g3 = pg[3];
    *(uint4*)(rowp + 64 + q * 16) =
        make_uint4(pack2(g0.x, g0.y), pack2(g0.z, g0.w), pack2(g1.x, g1.y), pack2(g1.z, g1.w));
    *(uint4*)(rowp + 64 + q * 16 + 8) =
        make_uint4(pack2(g2.x, g2.y), pack2(g2.z, g2.w), pack2(g3.x, g3.y), pack2(g3.z, g3.w));
  } else {
    *(uint4*)(rowp + q * 16)          = make_uint4(0, 0, 0, 0);
    *(uint4*)(rowp + q * 16 + 8)      = make_uint4(0, 0, 0, 0);
    *(uint4*)(rowp + 64 + q * 16)     = make_uint4(0, 0, 0, 0);
    *(uint4*)(rowp + 64 + q * 16 + 8) = make_uint4(0, 0, 0, 0);
  }

  const int w = t >> 6, l = t & 63, quad = l >> 4, lr = l & 15;
  const int row0 = w * 16;
  f32x4 acc[16] = {};
  for (int grp = 0; grp < 4; ++grp) {
    const uint4* gw = (const uint4*)WcT + (long long)(grp * 64) * 16;  // 16 uint4/row
    uint4* lw = (uint4*)sW;                                            // 17/row padded
    {
      int o0 = t >> 4, s4 = t & 15;
      #pragma unroll
      for (int pp = 0; pp < 4; ++pp) {
        int o = pp * 16 + o0;
        lw[o * 17 + s4] = gw[o * 16 + s4];
      }
    }
    __syncthreads();
    #pragma unroll
    for (int kc = 0; kc < 4; ++kc) {
      short8 aF = *(const short8*)(sIn + (row0 + lr) * KLP + kc * 32 + quad * 8);
      #pragma unroll
      for (int nt = 0; nt < 4; ++nt) {
        short8 bF = *(const short8*)(sW + (nt * 16 + lr) * KLP + kc * 32 + quad * 8);
        acc[grp * 4 + nt] = __builtin_amdgcn_mfma_f32_16x16x32_bf16(aF, bF, acc[grp * 4 + nt], 0, 0, 0);
      }
    }
    __syncthreads();
  }

  #pragma unroll
  for (int nt = 0; nt < 4; ++nt) {
    #pragma unroll
    for (int rr = 0; rr < 4; ++rr) {
      int node2 = base_n + row0 + quad * 4 + rr;
      if (node2 < nNodes) {
        int col = nt * 16 + lr;
        long long off = (long long)node2 * 64 + col;
        float dg = (float)degA[node2];
        float iv = acc[nt][rr]      + sBG[col]       + dg * sB2h[col];
        float fv = acc[4 + nt][rr]  + sBG[64 + col]  + dg * sB2h[64 + col];
        float gv = acc[8 + nt][rr]  + sBG[128 + col] + dg * sB2h[128 + col];
        float ov = acc[12 + nt][rr] + sBG[192 + col] + dg * sB2h[192 + col];
        float cOld = cin ? cin[off] : 0.f;
        float cN = sigm(fv) * cOld + sigm(iv) * tanh_f(gv);
        float hN = sigm(ov) * tanh_f(cN);
        cout[off] = cN;
        xbout[off] = f2bf(hN);
      }
    }
  }
}

// ---------------- readout (MFMA, bf16 input) ----------------
__global__ __launch_bounds__(256) void readout(
    const unsigned short* __restrict__ xq,
    const unsigned short* __restrict__ WrT,
    const float* __restrict__ gb, const float* __restrict__ fb,
    float* __restrict__ out, int nNodes)
{
  __shared__ unsigned short sX[64 * 72];
  __shared__ unsigned short sW[128 * 72];
  __shared__ float sOut[4][64];
  __shared__ float sGb[64], sFb[64];
  const int t = threadIdx.x;
  {
    const uint4* gw = (const uint4*)WrT;  // 1024 uint4
    uint4* lw = (uint4*)sW;               // 9/row padded
    #pragma unroll
    for (int pp = 0; pp < 4; ++pp) {
      int idx = t + pp * 256;
      int o = idx >> 3, s = idx & 7;
      lw[o * 9 + s] = gw[idx];
    }
    if (t < 50)      { sGb[t] = gb[t]; sFb[t] = fb[t]; }
    else if (t < 64) { sGb[t] = 0.f;   sFb[t] = 0.f; }
  }
  const int base = blockIdx.x * 64;
  const int nl = t >> 2, q = t & 3;
  const int node = base + nl;
  {
    uint4* dst = (uint4*)(sX + nl * 72 + q * 16);
    if (node < nNodes) {
      const uint4* px = (const uint4*)(xq + (long long)node * 64);
      dst[0] = px[q * 2];
      dst[1] = px[q * 2 + 1];
    } else {
      dst[0] = make_uint4(0, 0, 0, 0);
      dst[1] = make_uint4(0, 0, 0, 0);
    }
  }
  __syncthreads();

  const int w = t >> 6, l = t & 63, quad = l >> 4, lr = l & 15;
  f32x4 acc[8] = {};
  #pragma unroll
  for (int kc = 0; kc < 2; ++kc) {
    short8 aF = *(const short8*)(sX + (w * 16 + lr) * 72 + kc * 32 + quad * 8);
    #pragma unroll
    for (int n = 0; n < 8; ++n) {
      short8 bF = *(const short8*)(sW + (n * 16 + lr) * 72 + kc * 32 + quad * 8);
      acc[n] = __builtin_amdgcn_mfma_f32_16x16x32_bf16(aF, bF, acc[n], 0, 0, 0);
    }
  }
  #pragma unroll
  for (int n = 0; n < 4; ++n) {
    float val = 0.f;
    #pragma unroll
    for (int rr = 0; rr < 4; ++rr) {
      int nd = base + w * 16 + quad * 4 + rr;
      if (nd < nNodes) {
        int jj = n * 16 + lr;
        float gv = sigm(acc[n][rr] + sGb[jj]);
        float fv = acc[n + 4][rr] + sFb[jj];
        val += gv * fv;
      }
    }
    val += __shfl_xor(val, 16);
    val += __shfl_xor(val, 32);
    if (quad == 0) sOut[w][n * 16 + lr] = val;
  }
  __syncthreads();
  if (t < 50) {
    float s = sOut[0][t] + sOut[1][t] + sOut[2][t] + sOut[3][t];
    unsafeAtomicAdd(&out[t], s);
  }
}

extern "C" void kernel_launch(void* const* d_in, const int* in_sizes, int n_in,
                              void* d_out, int out_size, void* d_ws, size_t ws_size,
                              hipStream_t stream)
{
  const float* x      = (const float*)d_in[0];
  const float* ea     = (const float*)d_in[1];
  const int*   ei     = (const int*)d_in[2];
  const float* fe0_W1 = (const float*)d_in[3];
  const float* fe0_b1 = (const float*)d_in[4];
  const float* fe0_W2 = (const float*)d_in[5];
  const float* fe0_b2 = (const float*)d_in[6];
  const float* l0_Wih = (const float*)d_in[7];
  const float* l0_Whh = (const float*)d_in[8];
  const float* l0_bih = (const float*)d_in[9];
  const float* l0_bhh = (const float*)d_in[10];
  const float* fe1_W1 = (const float*)d_in[11];
  const float* fe1_b1 = (const float*)d_in[12];
  const float* fe1_W2 = (const float*)d_in[13];
  const float* fe1_b2 = (const float*)d_in[14];
  const float* l1_Wih = (const float*)d_in[15];
  const float* l1_Whh = (const float*)d_in[16];
  const float* l1_bih = (const float*)d_in[17];
  const float* l1_bhh = (const float*)d_in[18];
  const float* gm_W   = (const float*)d_in[19];
  const float* gm_b   = (const float*)d_in[20];
  const float* fm_W   = (const float*)d_in[21];
  const float* fm_b   = (const float*)d_in[22];

  const int N = in_sizes[0] / 64;    // 50000
  const int E = in_sizes[1] / 32;    // 800000
  const int* srcI = ei;
  const int* dstI = ei + E;

  char* ws = (char*)d_ws;
  unsigned short* xb0     = (unsigned short*)(ws + 0);           //  6,400,000
  unsigned short* xb1     = (unsigned short*)(ws + 6400000);     //  6,400,000
  float*          aggrH   = (float*)(ws + 12800000);             // 12,800,000
  float*          cbuf    = (float*)(ws + 25600000);             // 12,800,000
  int*            eidS    = (int*)(ws + 38400000);               //  3,200,000
  int*            srcS    = (int*)(ws + 41600000);               //  3,200,000
  int4*           segInfo = (int4*)(ws + 44800000);              //  1,600,128
  int*            histA   = (int*)(ws + 46400128);               //    200,000
  int*            curA    = (int*)(ws + 46600128);               //    200,000
  unsigned short* W1T     = (unsigned short*)(ws + 46800128);    //     40,960
  unsigned short* WcT     = (unsigned short*)(ws + 46841088);    //    131,072
  float*          bG      = (float*)(ws + 46972160);             //      2,048
  float*          b2h     = (float*)(ws + 46974208);             //      2,048
  unsigned short* WrT     = (unsigned short*)(ws + 46976256);    //     16,384
  int*            nSegPtr = (int*)(ws + 46992640);               //          4 (+60 pad)
  int2*           blockTot  = (int2*)(ws + 46992704);            //      2,048
  int2*           blockBase = (int2*)(ws + 46994752);            //      2,048

  hipMemsetAsync(d_out, 0, out_size * sizeof(float), stream);
  hipMemsetAsync(histA, 0, (size_t)N * 4, stream);

  prep_simple<<<(2 * 26880 + 8192 + 255) / 256, 256, 0, stream>>>(
      fe0_W1, l0_Wih, l0_bih, l0_bhh,
      fe1_W1, l1_Wih, l1_bih, l1_bhh,
      gm_W, fm_W, W1T, WcT, bG, WrT);
  prep_merge<<<(33280 + 255) / 256, 256, 0, stream>>>(
      fe0_W2, l0_Whh, fe0_b2, fe1_W2, l1_Whh, fe1_b2, WcT, b2h);
  convert_x<<<(N * 64 + 255) / 256, 256, 0, stream>>>(x, xb0, N * 64);

  const int nb = (N + 255) / 256;
  hist_kernel<<<(E + 255) / 256, 256, 0, stream>>>(dstI, histA, E);
  scan_part<<<nb, 256, 0, stream>>>(histA, blockTot, N);
  scan_mid<<<1, 256, 0, stream>>>(blockTot, blockBase, nSegPtr, nb);
  scan_final<<<nb, 256, 0, stream>>>(histA, blockBase, curA, segInfo, N);
  scatter_eid2<<<(E + 255) / 256, 256, 0, stream>>>(srcI, dstI, curA, eidS, srcS, E);

  const int nodeBlocks = (N + 63) / 64;

  // step 0
  hipMemsetAsync(aggrH, 0, (size_t)N * 64 * 4, stream);
  edge_gemm2<<<2048, 256, 0, stream>>>(xb0, ea, eidS, srcS, segInfo, nSegPtr,
                                       W1T, fe0_b1, aggrH);
  lstm3<<<nodeBlocks, 256, 0, stream>>>(xb0, aggrH, nullptr, cbuf, WcT, bG, b2h,
                                        histA, xb1, N);

  // step 1
  hipMemsetAsync(aggrH, 0, (size_t)N * 64 * 4, stream);
  edge_gemm2<<<2048, 256, 0, stream>>>(xb1, ea, eidS, srcS, segInfo, nSegPtr,
                                       W1T + 10240, fe1_b1, aggrH);
  lstm3<<<nodeBlocks, 256, 0, stream>>>(xb1, aggrH, cbuf, cbuf, WcT + 32768,
                                        bG + 256, b2h + 256, histA, xb0, N);

  readout<<<nodeBlocks, 256, 0, stream>>>(xb0, WrT, gm_b, fm_b, (float*)d_out, N);
}

// Round 9
// 479.253 us; speedup vs baseline: 1.3186x; 1.3186x over previous
//
#include <hip/hip_runtime.h>
#include <hip/hip_bf16.h>

using short8 = __attribute__((ext_vector_type(8))) short;
using f32x4  = __attribute__((ext_vector_type(4))) float;

#define KLP 136   // padded K=128 row stride for LSTM

__device__ __forceinline__ unsigned short f2bf(float f) {
  unsigned u = __float_as_uint(f);
  u += 0x7FFFu + ((u >> 16) & 1u);
  return (unsigned short)(u >> 16);
}
__device__ __forceinline__ unsigned pack2(float a, float b) {
  return (unsigned)f2bf(a) | ((unsigned)f2bf(b) << 16);
}
#if __has_builtin(__builtin_amdgcn_rcpf)
__device__ __forceinline__ float fast_rcp(float x) { return __builtin_amdgcn_rcpf(x); }
#else
__device__ __forceinline__ float fast_rcp(float x) { return 1.f / x; }
#endif
__device__ __forceinline__ float sigm(float x) { return fast_rcp(1.f + __expf(-x)); }
__device__ __forceinline__ float tanh_f(float x) { return fmaf(2.f, sigm(2.f * x), -1.f); }

// ---------------- prep: simple transposes + bf16 casts ----------------
__global__ __launch_bounds__(256) void prep_simple(
    const float* __restrict__ W1_0, const float* __restrict__ Wih0,
    const float* __restrict__ bih0, const float* __restrict__ bhh0,
    const float* __restrict__ W1_1, const float* __restrict__ Wih1,
    const float* __restrict__ bih1, const float* __restrict__ bhh1,
    const float* __restrict__ gmW, const float* __restrict__ fmW,
    unsigned short* __restrict__ W1T,  // [2][64*160] out-major
    unsigned short* __restrict__ WcT,  // [2][256*128] out-major (x-part cols 0..63)
    float* __restrict__ bG,            // [2][256]
    unsigned short* __restrict__ WrT)  // [128][64]
{
  int t = blockIdx.x * 256 + threadIdx.x;
  const int per = 10240 + 16384 + 256;  // 26880
  if (t >= 2 * per + 8192) return;
  if (t >= 2 * per) {
    int r2 = t - 2 * per;
    int o = r2 >> 6, k = r2 & 63;
    float v = 0.f;
    if (o < 50) v = gmW[k * 50 + o];
    else if (o >= 64 && o < 114) v = fmW[k * 50 + (o - 64)];
    WrT[o * 64 + k] = f2bf(v);
    return;
  }
  int step = t / per, r = t % per;
  const float* W1  = step ? W1_1 : W1_0;
  const float* Wih = step ? Wih1 : Wih0;
  const float* bih = step ? bih1 : bih0;
  const float* bhh = step ? bhh1 : bhh0;
  if (r < 10240) {
    int o = r / 160, k = r % 160;
    W1T[step * 10240 + o * 160 + k] = f2bf(W1[k * 64 + o]);
  } else if (r < 26624) {
    int rr = r - 10240;
    int g = rr >> 6, k = rr & 63;
    WcT[step * 32768 + g * 128 + k] = f2bf(Wih[k * 256 + g]);
  } else {
    int g = r - 26624;
    bG[step * 256 + g] = bih[g] + bhh[g];
  }
}

// ---------------- prep: merged weight  Wc_h' = W2 @ Whh,  b2h = b2 @ Whh ----------------
__global__ __launch_bounds__(256) void prep_merge(
    const float* __restrict__ W2_0, const float* __restrict__ Whh0, const float* __restrict__ b2_0,
    const float* __restrict__ W2_1, const float* __restrict__ Whh1, const float* __restrict__ b2_1,
    unsigned short* __restrict__ WcT,  // [2][256*128] (h-part cols 64..127)
    float* __restrict__ b2h)           // [2][256]
{
  int t = blockIdx.x * 256 + threadIdx.x;
  if (t < 32768) {
    int step = t >> 14, r = t & 16383;
    int g = r >> 6, k = r & 63;
    const float* W2  = step ? W2_1 : W2_0;
    const float* Whh = step ? Whh1 : Whh0;
    float v = 0.f;
    for (int j = 0; j < 64; ++j) v = fmaf(W2[k * 64 + j], Whh[j * 256 + g], v);
    WcT[step * 32768 + g * 128 + 64 + k] = f2bf(v);
  } else if (t < 33280) {
    int r = t - 32768;
    int step = r >> 8, g = r & 255;
    const float* b2  = step ? b2_1 : b2_0;
    const float* Whh = step ? Whh1 : Whh0;
    float v = 0.f;
    for (int j = 0; j < 64; ++j) v = fmaf(b2[j], Whh[j * 256 + g], v);
    b2h[step * 256 + g] = v;
  }
}

__global__ __launch_bounds__(256) void convert_x(
    const float* __restrict__ x, unsigned short* __restrict__ xb, int n)
{
  int i = blockIdx.x * 256 + threadIdx.x;
  if (i < n) xb[i] = f2bf(x[i]);
}

// ---------------- sort: hist -> 3-phase scan (+segment build) -> single-pass permute ----------------
__global__ __launch_bounds__(256) void hist_kernel(
    const int* __restrict__ dstI, int* __restrict__ hist, int E)
{
  int e = blockIdx.x * 256 + threadIdx.x;
  if (e < E) atomicAdd(&hist[dstI[e]], 1);
}

__global__ __launch_bounds__(256) void scan_part(
    const int* __restrict__ hist, int2* __restrict__ blockTot, int N)
{
  __shared__ int sD[256], sS[256];
  int t = threadIdx.x;
  int n = blockIdx.x * 256 + t;
  int d = (n < N) ? hist[n] : 0;
  int sg = (d + 15) >> 4;
  sD[t] = d; sS[t] = sg;
  __syncthreads();
  #pragma unroll
  for (int off = 128; off; off >>= 1) {
    if (t < off) { sD[t] += sD[t + off]; sS[t] += sS[t + off]; }
    __syncthreads();
  }
  if (t == 0) blockTot[blockIdx.x] = make_int2(sD[0], sS[0]);
}

__global__ __launch_bounds__(256) void scan_mid(
    const int2* __restrict__ blockTot, int2* __restrict__ blockBase,
    int* __restrict__ nSegTot, int nb)
{
  __shared__ int sD[256], sS[256];
  int t = threadIdx.x;
  int d = 0, s = 0;
  if (t < nb) { int2 v = blockTot[t]; d = v.x; s = v.y; }
  sD[t] = d; sS[t] = s;
  __syncthreads();
  #pragma unroll
  for (int off = 1; off < 256; off <<= 1) {
    int vd = (t >= off) ? sD[t - off] : 0;
    int vs = (t >= off) ? sS[t - off] : 0;
    __syncthreads();
    sD[t] += vd; sS[t] += vs;
    __syncthreads();
  }
  if (t < nb) blockBase[t] = make_int2(sD[t] - d, sS[t] - s);
  if (t == nb - 1) *nSegTot = sS[t];
}

__global__ __launch_bounds__(256) void scan_final(
    const int* __restrict__ hist, const int2* __restrict__ blockBase,
    int* __restrict__ cursor, int4* __restrict__ segInfo, int N)
{
  __shared__ int sD[256], sS[256];
  int t = threadIdx.x;
  int n = blockIdx.x * 256 + t;
  int d = (n < N) ? hist[n] : 0;
  int sg = (d + 15) >> 4;
  sD[t] = d; sS[t] = sg;
  __syncthreads();
  #pragma unroll
  for (int off = 1; off < 256; off <<= 1) {
    int vd = (t >= off) ? sD[t - off] : 0;
    int vs = (t >= off) ? sS[t - off] : 0;
    __syncthreads();
    sD[t] += vd; sS[t] += vs;
    __syncthreads();
  }
  if (n < N) {
    int2 bb = blockBase[blockIdx.x];
    int degBase = bb.x + sD[t] - d;
    int segBase = bb.y + sS[t] - sg;
    cursor[n] = degBase;
    for (int j = 0; j < sg; ++j)
      segInfo[segBase + j] = make_int4(degBase + j * 16, n, min(d - j * 16, 16), 0);
  }
}

// single-pass permute: coalesced ea read, random srcS(4B)+eaS(64B bf16) writes
__global__ __launch_bounds__(256) void scatter_perm(
    const int* __restrict__ srcI, const int* __restrict__ dstI,
    const float* __restrict__ ea, int* __restrict__ cursor,
    int* __restrict__ srcS, unsigned short* __restrict__ eaS, int E)
{
  int e = blockIdx.x * 256 + threadIdx.x;
  if (e >= E) return;
  int d = dstI[e];
  int p = atomicAdd(&cursor[d], 1);
  srcS[p] = srcI[e];
  const float4* pe = (const float4*)(ea + (long long)e * 32);
  float4 a0 = pe[0], a1 = pe[1], a2 = pe[2], a3 = pe[3];
  float4 a4 = pe[4], a5 = pe[5], a6 = pe[6], a7 = pe[7];
  uint4* out = (uint4*)(eaS + (long long)p * 32);
  out[0] = make_uint4(pack2(a0.x, a0.y), pack2(a0.z, a0.w), pack2(a1.x, a1.y), pack2(a1.z, a1.w));
  out[1] = make_uint4(pack2(a2.x, a2.y), pack2(a2.z, a2.w), pack2(a3.x, a3.y), pack2(a3.z, a3.w));
  out[2] = make_uint4(pack2(a4.x, a4.y), pack2(a4.z, a4.w), pack2(a5.x, a5.y), pack2(a5.z, a5.w));
  out[3] = make_uint4(pack2(a6.x, a6.y), pack2(a6.z, a6.w), pack2(a7.x, a7.y), pack2(a7.z, a7.w));
}

// ---------------- edge GEMM: zero LDS / zero barriers, coalesced eaS/srcS, src prefetch ----------------
// wave = one 16-edge segment of one dst node.
__global__ __launch_bounds__(256) void edge_gemm_reg(
    const unsigned short* __restrict__ xb,     // [N][64] bf16
    const unsigned short* __restrict__ eaS,    // [E][32] bf16, dst-sorted
    const int* __restrict__ srcS,              // [E] dst-sorted
    const int4* __restrict__ segInfo,          // [nSeg] {start,node,cnt,_}
    const int* __restrict__ nSegPtr,
    const unsigned short* __restrict__ W1T,    // [64][160] bf16 out-major
    const float* __restrict__ b1,
    float* __restrict__ aggrH)                 // [N][64] f32 (pre-zeroed)
{
  const int t = threadIdx.x;
  const int w = t >> 6, l = t & 63;
  const int quad = l >> 4, lr = l & 15;

  // loop-invariant: W1 B-fragments + bias
  short8 bF[5][4];
  #pragma unroll
  for (int kc = 0; kc < 5; ++kc)
    #pragma unroll
    for (int n = 0; n < 4; ++n)
      bF[kc][n] = *(const short8*)(W1T + (n * 16 + lr) * 160 + kc * 32 + quad * 8);
  float bb[4];
  #pragma unroll
  for (int n = 0; n < 4; ++n) bb[n] = b1[n * 16 + lr];

  const int nSeg = *nSegPtr;
  const int W = gridDim.x * 4;
  int s = blockIdx.x * 4 + w;
  if (s >= nSeg) return;
  int4 si = segInfo[s];
  int src = srcS[si.x + min(lr, si.z - 1)];   // first segment's src, loaded early

  while (true) {
    const int sn = s + W;
    const bool more = sn < nSeg;
    int4 si_n = si;
    if (more) si_n = segInfo[sn];   // prefetch next descriptor

    const int start = si.x, node = si.y, cnt = si.z;
    const int er = min(lr, cnt - 1);            // clamp pad rows to a valid edge

    const short8* pd = (const short8*)(xb + (long long)node * 64);
    const short8* ps = (const short8*)(xb + (long long)src * 64);
    const short8* pe = (const short8*)(eaS + (long long)(start + er) * 32);
    short8 a0 = pd[quad];       // x[dst], k 0..31   (wave-uniform row)
    short8 a1 = pd[4 + quad];   // x[dst], k 32..63
    short8 a2 = ps[quad];       // x[src], k 64..95
    short8 a3 = ps[4 + quad];   // x[src], k 96..127
    short8 a4 = pe[quad];       // ea,     k 128..159

    // prefetch next segment's src index while MFMAs run
    int src_n = src;
    if (more) src_n = srcS[si_n.x + min(lr, si_n.z - 1)];

    f32x4 acc[4] = {};
    #pragma unroll
    for (int n = 0; n < 4; ++n) acc[n] = __builtin_amdgcn_mfma_f32_16x16x32_bf16(a0, bF[0][n], acc[n], 0, 0, 0);
    #pragma unroll
    for (int n = 0; n < 4; ++n) acc[n] = __builtin_amdgcn_mfma_f32_16x16x32_bf16(a1, bF[1][n], acc[n], 0, 0, 0);
    #pragma unroll
    for (int n = 0; n < 4; ++n) acc[n] = __builtin_amdgcn_mfma_f32_16x16x32_bf16(a2, bF[2][n], acc[n], 0, 0, 0);
    #pragma unroll
    for (int n = 0; n < 4; ++n) acc[n] = __builtin_amdgcn_mfma_f32_16x16x32_bf16(a3, bF[3][n], acc[n], 0, 0, 0);
    #pragma unroll
    for (int n = 0; n < 4; ++n) acc[n] = __builtin_amdgcn_mfma_f32_16x16x32_bf16(a4, bF[4][n], acc[n], 0, 0, 0);

    // relu + mask pad rows + reduce 16 rows -> one atomic per output column
    #pragma unroll
    for (int n = 0; n < 4; ++n) {
      float sum = 0.f;
      #pragma unroll
      for (int rr = 0; rr < 4; ++rr) {
        float v = fmaxf(acc[n][rr] + bb[n], 0.f);
        sum += (quad * 4 + rr < cnt) ? v : 0.f;
      }
      sum += __shfl_xor(sum, 16);
      sum += __shfl_xor(sum, 32);
      if (quad == 0) unsafeAtomicAdd(&aggrH[(long long)node * 64 + n * 16 + lr], sum);
    }

    if (!more) break;
    s = sn; si = si_n; src = src_n;
  }
}

// ---------------- LSTM cell: gates = [x | G] @ Wc' + bG + deg*b2h (bf16 h-path) ----------------
__global__ __launch_bounds__(256) void lstm3(
    const unsigned short* __restrict__ xbin,  // [N][64] bf16
    const float* __restrict__ aggrH,          // [N][64] f32 (Sum relu h1)
    const float* __restrict__ cin,            // may be null (c=0)
    float* __restrict__ cout,
    const unsigned short* __restrict__ WcT,   // [256][128] bf16 out-major (merged)
    const float* __restrict__ bG,             // [256]
    const float* __restrict__ b2h,            // [256]
    const int* __restrict__ degA,             // [N]
    unsigned short* __restrict__ xbout,       // [N][64] bf16
    int nNodes)
{
  __shared__ unsigned short sIn[64 * KLP];
  __shared__ unsigned short sW[64 * KLP];
  __shared__ float sBG[256], sB2h[256];
  const int t = threadIdx.x;
  sBG[t] = bG[t];
  sB2h[t] = b2h[t];

  const int base_n = blockIdx.x * 64;
  const int nl = t >> 2, q = t & 3;
  const int node = base_n + nl;
  unsigned short* rowp = sIn + nl * KLP;
  if (node < nNodes) {
    const uint4* px = (const uint4*)(xbin + (long long)node * 64);
    *(uint4*)(rowp + q * 16)     = px[q * 2];
    *(uint4*)(rowp + q * 16 + 8) = px[q * 2 + 1];
    const float4* pg = (const float4*)(aggrH + (long long)node * 64) + q * 4;
    float4 g0 = pg[0], g1 = pg[1], g2 = pg[2], g3 = pg[3];
    *(uint4*)(rowp + 64 + q * 16) =
        make_uint4(pack2(g0.x, g0.y), pack2(g0.z, g0.w), pack2(g1.x, g1.y), pack2(g1.z, g1.w));
    *(uint4*)(rowp + 64 + q * 16 + 8) =
        make_uint4(pack2(g2.x, g2.y), pack2(g2.z, g2.w), pack2(g3.x, g3.y), pack2(g3.z, g3.w));
  } else {
    *(uint4*)(rowp + q * 16)          = make_uint4(0, 0, 0, 0);
    *(uint4*)(rowp + q * 16 + 8)      = make_uint4(0, 0, 0, 0);
    *(uint4*)(rowp + 64 + q * 16)     = make_uint4(0, 0, 0, 0);
    *(uint4*)(rowp + 64 + q * 16 + 8) = make_uint4(0, 0, 0, 0);
  }

  const int w = t >> 6, l = t & 63, quad = l >> 4, lr = l & 15;
  const int row0 = w * 16;
  f32x4 acc[16] = {};
  for (int grp = 0; grp < 4; ++grp) {
    const uint4* gw = (const uint4*)WcT + (long long)(grp * 64) * 16;  // 16 uint4/row
    uint4* lw = (uint4*)sW;                                            // 17/row padded
    {
      int o0 = t >> 4, s4 = t & 15;
      #pragma unroll
      for (int pp = 0; pp < 4; ++pp) {
        int o = pp * 16 + o0;
        lw[o * 17 + s4] = gw[o * 16 + s4];
      }
    }
    __syncthreads();
    #pragma unroll
    for (int kc = 0; kc < 4; ++kc) {
      short8 aF = *(const short8*)(sIn + (row0 + lr) * KLP + kc * 32 + quad * 8);
      #pragma unroll
      for (int nt = 0; nt < 4; ++nt) {
        short8 bF = *(const short8*)(sW + (nt * 16 + lr) * KLP + kc * 32 + quad * 8);
        acc[grp * 4 + nt] = __builtin_amdgcn_mfma_f32_16x16x32_bf16(aF, bF, acc[grp * 4 + nt], 0, 0, 0);
      }
    }
    __syncthreads();
  }

  #pragma unroll
  for (int nt = 0; nt < 4; ++nt) {
    #pragma unroll
    for (int rr = 0; rr < 4; ++rr) {
      int node2 = base_n + row0 + quad * 4 + rr;
      if (node2 < nNodes) {
        int col = nt * 16 + lr;
        long long off = (long long)node2 * 64 + col;
        float dg = (float)degA[node2];
        float iv = acc[nt][rr]      + sBG[col]       + dg * sB2h[col];
        float fv = acc[4 + nt][rr]  + sBG[64 + col]  + dg * sB2h[64 + col];
        float gv = acc[8 + nt][rr]  + sBG[128 + col] + dg * sB2h[128 + col];
        float ov = acc[12 + nt][rr] + sBG[192 + col] + dg * sB2h[192 + col];
        float cOld = cin ? cin[off] : 0.f;
        float cN = sigm(fv) * cOld + sigm(iv) * tanh_f(gv);
        float hN = sigm(ov) * tanh_f(cN);
        cout[off] = cN;
        xbout[off] = f2bf(hN);
      }
    }
  }
}

// ---------------- readout (MFMA, bf16 input) ----------------
__global__ __launch_bounds__(256) void readout(
    const unsigned short* __restrict__ xq,
    const unsigned short* __restrict__ WrT,
    const float* __restrict__ gb, const float* __restrict__ fb,
    float* __restrict__ out, int nNodes)
{
  __shared__ unsigned short sX[64 * 72];
  __shared__ unsigned short sW[128 * 72];
  __shared__ float sOut[4][64];
  __shared__ float sGb[64], sFb[64];
  const int t = threadIdx.x;
  {
    const uint4* gw = (const uint4*)WrT;  // 1024 uint4
    uint4* lw = (uint4*)sW;               // 9/row padded
    #pragma unroll
    for (int pp = 0; pp < 4; ++pp) {
      int idx = t + pp * 256;
      int o = idx >> 3, s = idx & 7;
      lw[o * 9 + s] = gw[idx];
    }
    if (t < 50)      { sGb[t] = gb[t]; sFb[t] = fb[t]; }
    else if (t < 64) { sGb[t] = 0.f;   sFb[t] = 0.f; }
  }
  const int base = blockIdx.x * 64;
  const int nl = t >> 2, q = t & 3;
  const int node = base + nl;
  {
    uint4* dst = (uint4*)(sX + nl * 72 + q * 16);
    if (node < nNodes) {
      const uint4* px = (const uint4*)(xq + (long long)node * 64);
      dst[0] = px[q * 2];
      dst[1] = px[q * 2 + 1];
    } else {
      dst[0] = make_uint4(0, 0, 0, 0);
      dst[1] = make_uint4(0, 0, 0, 0);
    }
  }
  __syncthreads();

  const int w = t >> 6, l = t & 63, quad = l >> 4, lr = l & 15;
  f32x4 acc[8] = {};
  #pragma unroll
  for (int kc = 0; kc < 2; ++kc) {
    short8 aF = *(const short8*)(sX + (w * 16 + lr) * 72 + kc * 32 + quad * 8);
    #pragma unroll
    for (int n = 0; n < 8; ++n) {
      short8 bF = *(const short8*)(sW + (n * 16 + lr) * 72 + kc * 32 + quad * 8);
      acc[n] = __builtin_amdgcn_mfma_f32_16x16x32_bf16(aF, bF, acc[n], 0, 0, 0);
    }
  }
  #pragma unroll
  for (int n = 0; n < 4; ++n) {
    float val = 0.f;
    #pragma unroll
    for (int rr = 0; rr < 4; ++rr) {
      int nd = base + w * 16 + quad * 4 + rr;
      if (nd < nNodes) {
        int jj = n * 16 + lr;
        float gv = sigm(acc[n][rr] + sGb[jj]);
        float fv = acc[n + 4][rr] + sFb[jj];
        val += gv * fv;
      }
    }
    val += __shfl_xor(val, 16);
    val += __shfl_xor(val, 32);
    if (quad == 0) sOut[w][n * 16 + lr] = val;
  }
  __syncthreads();
  if (t < 50) {
    float s = sOut[0][t] + sOut[1][t] + sOut[2][t] + sOut[3][t];
    unsafeAtomicAdd(&out[t], s);
  }
}

extern "C" void kernel_launch(void* const* d_in, const int* in_sizes, int n_in,
                              void* d_out, int out_size, void* d_ws, size_t ws_size,
                              hipStream_t stream)
{
  const float* x      = (const float*)d_in[0];
  const float* ea     = (const float*)d_in[1];
  const int*   ei     = (const int*)d_in[2];
  const float* fe0_W1 = (const float*)d_in[3];
  const float* fe0_b1 = (const float*)d_in[4];
  const float* fe0_W2 = (const float*)d_in[5];
  const float* fe0_b2 = (const float*)d_in[6];
  const float* l0_Wih = (const float*)d_in[7];
  const float* l0_Whh = (const float*)d_in[8];
  const float* l0_bih = (const float*)d_in[9];
  const float* l0_bhh = (const float*)d_in[10];
  const float* fe1_W1 = (const float*)d_in[11];
  const float* fe1_b1 = (const float*)d_in[12];
  const float* fe1_W2 = (const float*)d_in[13];
  const float* fe1_b2 = (const float*)d_in[14];
  const float* l1_Wih = (const float*)d_in[15];
  const float* l1_Whh = (const float*)d_in[16];
  const float* l1_bih = (const float*)d_in[17];
  const float* l1_bhh = (const float*)d_in[18];
  const float* gm_W   = (const float*)d_in[19];
  const float* gm_b   = (const float*)d_in[20];
  const float* fm_W   = (const float*)d_in[21];
  const float* fm_b   = (const float*)d_in[22];

  const int N = in_sizes[0] / 64;    // 50000
  const int E = in_sizes[1] / 32;    // 800000
  const int* srcI = ei;
  const int* dstI = ei + E;

  char* ws = (char*)d_ws;
  unsigned short* xb0     = (unsigned short*)(ws + 0);           //  6,400,000
  unsigned short* xb1     = (unsigned short*)(ws + 6400000);     //  6,400,000
  float*          aggrH   = (float*)(ws + 12800000);             // 12,800,000
  float*          cbuf    = (float*)(ws + 25600000);             // 12,800,000
  unsigned short* eaS     = (unsigned short*)(ws + 38400000);    // 51,200,000
  int*            srcS    = (int*)(ws + 89601024);               //  3,200,000 (+1KB slack)
  int4*           segInfo = (int4*)(ws + 92801088);              //  1,600,128
  int*            histA   = (int*)(ws + 94401280);               //    200,000
  int*            curA    = (int*)(ws + 94601280);               //    200,000
  unsigned short* W1T     = (unsigned short*)(ws + 94801280);    //     40,960
  unsigned short* WcT     = (unsigned short*)(ws + 94842240);    //    131,072
  float*          bG      = (float*)(ws + 94973312);             //      2,048
  float*          b2h     = (float*)(ws + 94975360);             //      2,048
  unsigned short* WrT     = (unsigned short*)(ws + 94977408);    //     16,384
  int*            nSegPtr = (int*)(ws + 94993792);               //          4 (+60 pad)
  int2*           blockTot  = (int2*)(ws + 94993856);            //      2,048
  int2*           blockBase = (int2*)(ws + 94995904);            //      2,048

  hipMemsetAsync(d_out, 0, out_size * sizeof(float), stream);
  hipMemsetAsync(histA, 0, (size_t)N * 4, stream);

  prep_simple<<<(2 * 26880 + 8192 + 255) / 256, 256, 0, stream>>>(
      fe0_W1, l0_Wih, l0_bih, l0_bhh,
      fe1_W1, l1_Wih, l1_bih, l1_bhh,
      gm_W, fm_W, W1T, WcT, bG, WrT);
  prep_merge<<<(33280 + 255) / 256, 256, 0, stream>>>(
      fe0_W2, l0_Whh, fe0_b2, fe1_W2, l1_Whh, fe1_b2, WcT, b2h);
  convert_x<<<(N * 64 + 255) / 256, 256, 0, stream>>>(x, xb0, N * 64);

  const int nb = (N + 255) / 256;
  hist_kernel<<<(E + 255) / 256, 256, 0, stream>>>(dstI, histA, E);
  scan_part<<<nb, 256, 0, stream>>>(histA, blockTot, N);
  scan_mid<<<1, 256, 0, stream>>>(blockTot, blockBase, nSegPtr, nb);
  scan_final<<<nb, 256, 0, stream>>>(histA, blockBase, curA, segInfo, N);
  scatter_perm<<<(E + 255) / 256, 256, 0, stream>>>(srcI, dstI, ea, curA, srcS, eaS, E);

  const int nodeBlocks = (N + 63) / 64;

  // step 0
  hipMemsetAsync(aggrH, 0, (size_t)N * 64 * 4, stream);
  edge_gemm_reg<<<2048, 256, 0, stream>>>(xb0, eaS, srcS, segInfo, nSegPtr,
                                          W1T, fe0_b1, aggrH);
  lstm3<<<nodeBlocks, 256, 0, stream>>>(xb0, aggrH, nullptr, cbuf, WcT, bG, b2h,
                                        histA, xb1, N);

  // step 1
  hipMemsetAsync(aggrH, 0, (size_t)N * 64 * 4, stream);
  edge_gemm_reg<<<2048, 256, 0, stream>>>(xb1, eaS, srcS, segInfo, nSegPtr,
                                          W1T + 10240, fe1_b1, aggrH);
  lstm3<<<nodeBlocks, 256, 0, stream>>>(xb1, aggrH, cbuf, cbuf, WcT + 32768,
                                        bG + 256, b2h + 256, histA, xb0, N);

  readout<<<nodeBlocks, 256, 0, stream>>>(xb0, WrT, gm_b, fm_b, (float*)d_out, N);
}